// Round 4
// baseline (1073.185 us; speedup 1.0000x reference)
//
#include <hip/hip_runtime.h>

#define N_LSTM 16
#define ISZ 128
#define HSZ 128
#define BSZ 32
#define TSZ 512
#define G4H 512
#define XROW (N_LSTM * ISZ)   // 2048
#define OROW (N_LSTM * HSZ)   // 2048

typedef __attribute__((ext_vector_type(8))) short s16x8;
typedef __attribute__((ext_vector_type(4))) float f32x4;

static __device__ __forceinline__ unsigned short f2bf(float f) {
    unsigned int u = __builtin_bit_cast(unsigned int, f);
    u += 0x7fffu + ((u >> 16) & 1u);
    return (unsigned short)(u >> 16);
}

static __device__ __forceinline__ float bf2f(unsigned short s) {
    unsigned int u = ((unsigned int)s) << 16;
    return __builtin_bit_cast(float, u);
}

static __device__ __forceinline__ float fast_sigmoid(float x) {
    float e = __expf(-x);
    return __builtin_amdgcn_rcpf(1.0f + e);
}

static __device__ __forceinline__ float fast_tanh(float x) {
    x = fminf(fmaxf(x, -20.0f), 20.0f);
    float e = __expf(-2.0f * x);
    return (1.0f - e) * __builtin_amdgcn_rcpf(1.0f + e);
}

// ---------------------------------------------------------------------------
// Kernel A: xp[t*32+b][n][4H] (bf16) = x[b][t][n,:] @ Wih[n]^T + (bih+bhh)[n]
// Block: 128 rows (of T*B=16384) x 128 cols (of 4H), K=128. 4 waves.
// Grid: 128 row-blocks x 4 col-blocks x 16 n = 8192 blocks. LDS 34 KB.
// ---------------------------------------------------------------------------
__global__ __launch_bounds__(256, 2) void xproj_gemm(
    const float* __restrict__ x, const float* __restrict__ Wih,
    const float* __restrict__ bih, const float* __restrict__ bhh,
    unsigned short* __restrict__ ws)
{
    __shared__ __align__(16) unsigned short xs[128][136];

    const int tid = threadIdx.x;
    const int w  = tid >> 6;
    const int ln = tid & 63;
    const int lm = ln & 15;
    const int lq = ln >> 4;
    const int bx  = blockIdx.x;
    const int nt  = bx & 3;             // 128-col group
    const int mtb = (bx >> 2) & 127;    // 128-row block
    const int n   = bx >> 9;            // lstm index
    const int R0  = mtb * 128;

    // stage x tile (128 rows x 128 k) as bf16
    #pragma unroll 1
    for (int i = 0; i < 16; ++i) {
        int flat = tid + i * 256;
        int row  = flat >> 5;
        int c4   = (flat & 31) * 4;
        int rw   = R0 + row;
        int t = rw >> 5, b = rw & 31;
        const float4 v = *(const float4*)(x + ((size_t)b * TSZ + t) * XROW + n * ISZ + c4);
        unsigned int lo = (unsigned int)f2bf(v.x) | ((unsigned int)f2bf(v.y) << 16);
        unsigned int hi = (unsigned int)f2bf(v.z) | ((unsigned int)f2bf(v.w) << 16);
        *(uint2*)&xs[row][c4] = make_uint2(lo, hi);
    }
    __syncthreads();

    // 2 col-groups of 64 cols each
    #pragma unroll 1
    for (int cg = 0; cg < 2; ++cg) {
        const int C0 = nt * 128 + cg * 64;
        s16x8 bfr[4][4];
        float bs[4];
        #pragma unroll
        for (int ct = 0; ct < 4; ++ct) {
            const int col = C0 + ct * 16 + lm;
            bs[ct] = bih[n * G4H + col] + bhh[n * G4H + col];
            #pragma unroll
            for (int kt = 0; kt < 4; ++kt) {
                const float* p = Wih + ((size_t)n * G4H + col) * ISZ + kt * 32 + lq * 8;
                s16x8 f;
                #pragma unroll
                for (int j = 0; j < 8; ++j) f[j] = (short)f2bf(p[j]);
                bfr[ct][kt] = f;
            }
        }
        #pragma unroll 1
        for (int mt = 0; mt < 2; ++mt) {
            const int lr = w * 32 + mt * 16;
            s16x8 a[4];
            #pragma unroll
            for (int kt = 0; kt < 4; ++kt)
                a[kt] = *(const s16x8*)&xs[lr + lm][kt * 32 + lq * 8];
            f32x4 acc[4];
            #pragma unroll
            for (int ct = 0; ct < 4; ++ct)
                acc[ct] = (f32x4){bs[ct], bs[ct], bs[ct], bs[ct]};
            #pragma unroll
            for (int kt = 0; kt < 4; ++kt)
                #pragma unroll
                for (int ct = 0; ct < 4; ++ct)
                    acc[ct] = __builtin_amdgcn_mfma_f32_16x16x32_bf16(a[kt], bfr[ct][kt], acc[ct], 0, 0, 0);
            #pragma unroll
            for (int ct = 0; ct < 4; ++ct)
                #pragma unroll
                for (int r = 0; r < 4; ++r) {
                    int rw = R0 + lr + lq * 4 + r;
                    size_t off = ((size_t)rw * N_LSTM + n) * G4H + C0 + ct * 16 + lm;
                    ws[off] = f2bf(acc[ct][r]);
                }
        }
    }
}

// ---------------------------------------------------------------------------
// Kernel B: recurrence. Block = (n, batch-half). 8 waves; wave owns 16 hidden
// units x 4 gates. Whh in registers as B-frags. xp from ws, prefetch dist 2.
// ---------------------------------------------------------------------------
static __device__ __forceinline__ void load_px(const unsigned short* __restrict__ xp,
                                               int t, int b0, int n, int wv, int lm, int lq,
                                               float px[16])
{
    #pragma unroll
    for (int r = 0; r < 4; ++r) {
        const unsigned short* p = xp
            + ((size_t)((t * BSZ + b0 + lq * 4 + r) * N_LSTM + n)) * G4H + wv * 16 + lm;
        #pragma unroll
        for (int g = 0; g < 4; ++g)
            px[r * 4 + g] = bf2f(p[g * 128]);
    }
}

__global__ __launch_bounds__(512, 2) void lstm_rec(
    const unsigned short* __restrict__ xp, const float* __restrict__ Whh,
    float* __restrict__ out)
{
    __shared__ __align__(16) unsigned short hbuf[2][16][136];

    const int tid = threadIdx.x;
    const int wv  = tid >> 6;
    const int ln  = tid & 63;
    const int lm  = ln & 15;
    const int lq  = ln >> 4;
    const int n    = blockIdx.x >> 1;
    const int half = blockIdx.x & 1;
    const int b0   = half * 16;

    // Whh B-frags (once)
    s16x8 whh[4][4];
    #pragma unroll
    for (int g = 0; g < 4; ++g) {
        const int col = g * 128 + wv * 16 + lm;
        #pragma unroll
        for (int kt = 0; kt < 4; ++kt) {
            const float* ph = Whh + ((size_t)n * G4H + col) * HSZ + kt * 32 + lq * 8;
            s16x8 b;
            #pragma unroll
            for (int j = 0; j < 8; ++j) b[j] = (short)f2bf(ph[j]);
            whh[g][kt] = b;
        }
    }

    for (int i = tid; i < 2 * 16 * 136; i += 512)
        ((unsigned short*)hbuf)[i] = 0;

    float cprev[4] = {0.f, 0.f, 0.f, 0.f};
    float hlast[4] = {0.f, 0.f, 0.f, 0.f};

    const int ocol = n * HSZ + wv * 16 + lm;
    size_t obase[4];
    #pragma unroll
    for (int r = 0; r < 4; ++r)
        obase[r] = (size_t)(b0 + lq * 4 + r) * TSZ * OROW + ocol;

    float pxc[16], pxn[16];
    load_px(xp, 0, b0, n, wv, lm, lq, pxc);
    load_px(xp, 1, b0, n, wv, lm, lq, pxn);

    size_t toff = 0;

    #pragma unroll 2
    for (int t = 0; t < TSZ; ++t) {
        const int buf = t & 1;
        __syncthreads();   // h(t-1) ready in hbuf[buf]

        s16x8 ah[4];
        #pragma unroll
        for (int kt = 0; kt < 4; ++kt)
            ah[kt] = *(const s16x8*)&hbuf[buf][lm][kt * 32 + lq * 8];

        // prefetch xp for t+2 (dist 2 covers HBM latency)
        float pxf[16];
        int t2 = (t + 2 < TSZ) ? t + 2 : TSZ - 1;
        load_px(xp, t2, b0, n, wv, lm, lq, pxf);

        f32x4 acc[4];
        #pragma unroll
        for (int g = 0; g < 4; ++g)
            acc[g] = (f32x4){pxc[g], pxc[4 + g], pxc[8 + g], pxc[12 + g]};

        #pragma unroll
        for (int kt = 0; kt < 4; ++kt)
            #pragma unroll
            for (int g = 0; g < 4; ++g)
                acc[g] = __builtin_amdgcn_mfma_f32_16x16x32_bf16(ah[kt], whh[g][kt], acc[g], 0, 0, 0);

        float hv[4];
        #pragma unroll
        for (int r = 0; r < 4; ++r) {
            float iv = fast_sigmoid(acc[0][r]);
            float fv = fast_sigmoid(acc[1][r]);
            float gv = fast_tanh(acc[2][r]);
            float ov = fast_sigmoid(acc[3][r]);
            float c  = fv * cprev[r] + iv * gv;
            cprev[r] = c;
            float h  = ov * fast_tanh(c);
            hv[r] = h;
            hlast[r] = h;
            hbuf[buf ^ 1][lq * 4 + r][wv * 16 + lm] = f2bf(h);
        }
        #pragma unroll
        for (int r = 0; r < 4; ++r)
            out[toff + obase[r]] = hv[r];
        toff += OROW;

        #pragma unroll
        for (int i = 0; i < 16; ++i) { pxc[i] = pxn[i]; pxn[i] = pxf[i]; }
    }

    const size_t hn_off = (size_t)BSZ * TSZ * OROW;
    const size_t cn_off = hn_off + (size_t)BSZ * OROW;
    #pragma unroll
    for (int r = 0; r < 4; ++r) {
        const size_t idx = (size_t)(b0 + lq * 4 + r) * OROW + ocol;
        out[hn_off + idx] = hlast[r];
        out[cn_off + idx] = cprev[r];
    }
}

// ---------------------------------------------------------------------------
// Fallback: round-1 fused kernel (used when ws is too small for xp).
// ---------------------------------------------------------------------------
__global__ __launch_bounds__(512, 2) void widelstm_fused(
    const float* __restrict__ x, const float* __restrict__ Wih,
    const float* __restrict__ Whh, const float* __restrict__ bih,
    const float* __restrict__ bhh, float* __restrict__ out)
{
    __shared__ __align__(16) unsigned short xbuf[2][16][136];
    __shared__ __align__(16) unsigned short hbuf[2][16][136];

    const int tid = threadIdx.x;
    const int wv  = tid >> 6;
    const int ln  = tid & 63;
    const int lm  = ln & 15;
    const int lq  = ln >> 4;
    const int n    = blockIdx.x >> 1;
    const int half = blockIdx.x & 1;
    const int b0   = half * 16;

    s16x8 wih[4][4], whh[4][4];
    float bias[4];
    #pragma unroll
    for (int g = 0; g < 4; ++g) {
        const int col = g * 128 + wv * 16 + lm;
        bias[g] = bih[n * G4H + col] + bhh[n * G4H + col];
        #pragma unroll
        for (int kt = 0; kt < 4; ++kt) {
            const float* pi = Wih + ((size_t)n * G4H + col) * ISZ + kt * 32 + lq * 8;
            const float* ph = Whh + ((size_t)n * G4H + col) * HSZ + kt * 32 + lq * 8;
            s16x8 a, b;
            #pragma unroll
            for (int j = 0; j < 8; ++j) { a[j] = (short)f2bf(pi[j]); b[j] = (short)f2bf(ph[j]); }
            wih[g][kt] = a; whh[g][kt] = b;
        }
    }

    for (int i = tid; i < 2 * 16 * 136; i += 512)
        ((unsigned short*)hbuf)[i] = 0;

    const int sr = tid >> 5;
    const int sc = (tid & 31) * 4;
    const float* xrow = x + (size_t)(b0 + sr) * TSZ * XROW + n * ISZ + sc;
    float4 xr = *(const float4*)(xrow);

    float cprev[4] = {0.f, 0.f, 0.f, 0.f};
    float hlast[4] = {0.f, 0.f, 0.f, 0.f};
    const int ocol = n * HSZ + wv * 16 + lm;

    #pragma unroll 1
    for (int t = 0; t < TSZ; ++t) {
        const int buf = t & 1;
        unsigned int lo = (unsigned int)f2bf(xr.x) | ((unsigned int)f2bf(xr.y) << 16);
        unsigned int hi = (unsigned int)f2bf(xr.z) | ((unsigned int)f2bf(xr.w) << 16);
        *(uint2*)&xbuf[buf][sr][sc] = make_uint2(lo, hi);
        __syncthreads();
        if (t + 1 < TSZ) xr = *(const float4*)(xrow + (size_t)(t + 1) * XROW);

        s16x8 ax[4], ah[4];
        #pragma unroll
        for (int kt = 0; kt < 4; ++kt) {
            ax[kt] = *(const s16x8*)&xbuf[buf][lm][kt * 32 + lq * 8];
            ah[kt] = *(const s16x8*)&hbuf[buf][lm][kt * 32 + lq * 8];
        }
        f32x4 acc[4];
        #pragma unroll
        for (int g = 0; g < 4; ++g) acc[g] = (f32x4){bias[g], bias[g], bias[g], bias[g]};
        #pragma unroll
        for (int kt = 0; kt < 4; ++kt)
            #pragma unroll
            for (int g = 0; g < 4; ++g) {
                acc[g] = __builtin_amdgcn_mfma_f32_16x16x32_bf16(ax[kt], wih[g][kt], acc[g], 0, 0, 0);
                acc[g] = __builtin_amdgcn_mfma_f32_16x16x32_bf16(ah[kt], whh[g][kt], acc[g], 0, 0, 0);
            }
        float* orow = out + (size_t)t * OROW + ocol;
        #pragma unroll
        for (int r = 0; r < 4; ++r) {
            float iv = fast_sigmoid(acc[0][r]);
            float fv = fast_sigmoid(acc[1][r]);
            float gv = fast_tanh(acc[2][r]);
            float ov = fast_sigmoid(acc[3][r]);
            float c  = fv * cprev[r] + iv * gv;
            cprev[r] = c;
            float h  = ov * fast_tanh(c);
            hlast[r] = h;
            const int row = lq * 4 + r;
            orow[(size_t)(b0 + row) * TSZ * OROW] = h;
            hbuf[buf ^ 1][row][wv * 16 + lm] = f2bf(h);
        }
    }

    const size_t hn_off = (size_t)BSZ * TSZ * OROW;
    const size_t cn_off = hn_off + (size_t)BSZ * OROW;
    #pragma unroll
    for (int r = 0; r < 4; ++r) {
        const int row = lq * 4 + r;
        const size_t idx = (size_t)(b0 + row) * OROW + ocol;
        out[hn_off + idx] = hlast[r];
        out[cn_off + idx] = cprev[r];
    }
}

extern "C" void kernel_launch(void* const* d_in, const int* in_sizes, int n_in,
                              void* d_out, int out_size, void* d_ws, size_t ws_size,
                              hipStream_t stream) {
    const float* x   = (const float*)d_in[0];
    const float* Wih = (const float*)d_in[1];
    const float* Whh = (const float*)d_in[2];
    const float* bih = (const float*)d_in[3];
    const float* bhh = (const float*)d_in[4];
    float* out = (float*)d_out;

    const size_t need_bf16 = (size_t)TSZ * BSZ * N_LSTM * G4H * 2;  // 268 MB
    if (ws_size >= need_bf16) {
        unsigned short* xp = (unsigned short*)d_ws;
        xproj_gemm<<<dim3(8192), dim3(256), 0, stream>>>(x, Wih, bih, bhh, xp);
        lstm_rec<<<dim3(32), dim3(512), 0, stream>>>(xp, Whh, out);
    } else {
        widelstm_fused<<<dim3(32), dim3(512), 0, stream>>>(x, Wih, Whh, bih, bhh, out);
    }
}